// Round 3
// baseline (112.124 us; speedup 1.0000x reference)
//
#include <hip/hip_runtime.h>

// loss_separation: sum_{b, i != j} exp(-0.5 * ||kp[b,i] - kp[b,j]||)
// B=32, N=2048 fp32 -> scalar fp32.
// Symmetry: sum = 2 * sum_{i<j}. Compute upper-triangular 128x128 tile pairs:
// off-diagonal tiles weighted x2, diagonal tiles x1 with exact -1.0 diag fix
// (d2==0 exactly -> sqrt->0, exp->1).

#define BATCHES 32
#define NPTS 2048
#define TILE 128
#define TTILES (NPTS / TILE)                 // 16
#define NTPAIRS (TTILES * (TTILES + 1) / 2)  // 136

__global__ __launch_bounds__(TILE)
void loss_sep_kernel(const float2* __restrict__ kp, float* __restrict__ out) {
    const int b = blockIdx.y;

    // Decode upper-triangular tile pair (ti <= tj); uniform scalar loop <=16 iters.
    int t = blockIdx.x;
    int ti = 0;
    while (t >= TTILES - ti) { t -= TTILES - ti; ++ti; }
    const int tj = ti + t;
    const bool diag = (ti == tj);

    const int i0 = ti * TILE;
    const int j0 = tj * TILE;
    const int tid = threadIdx.x;

    __shared__ float2 kj[TILE];
    kj[tid] = kp[(size_t)b * NPTS + j0 + tid];          // 8B/lane coalesced, 1 KB
    const float2 ki = kp[(size_t)b * NPTS + i0 + tid];
    __syncthreads();

    const float4* kj4 = reinterpret_cast<const float4*>(kj);
    const float c = -0.72134752044448169f;  // -0.5 * log2(e)

    float acc0 = 0.0f, acc1 = 0.0f;
    #pragma unroll 8
    for (int jj = 0; jj < TILE / 2; ++jj) {
        const float4 v = kj4[jj];           // ds_read_b128, wave-uniform broadcast
        const float dx0 = ki.x - v.x, dy0 = ki.y - v.y;
        const float dx1 = ki.x - v.z, dy1 = ki.y - v.w;
        const float s0 = __builtin_amdgcn_sqrtf(dx0 * dx0 + dy0 * dy0);
        const float s1 = __builtin_amdgcn_sqrtf(dx1 * dx1 + dy1 * dy1);
        acc0 += __builtin_amdgcn_exp2f(c * s0);  // exp(-0.5*s) == exp2(c*s)
        acc1 += __builtin_amdgcn_exp2f(c * s1);
    }
    float acc = acc0 + acc1;
    if (diag) acc -= 1.0f;  // remove exact j==i term (exp(0)=1)

    // Wave-64 butterfly reduce
    #pragma unroll
    for (int off = 32; off > 0; off >>= 1)
        acc += __shfl_down(acc, off, 64);

    __shared__ float wsum[TILE / 64];
    if ((tid & 63) == 0) wsum[tid >> 6] = acc;
    __syncthreads();

    if (tid == 0) {
        float tot = wsum[0] + wsum[1];
        if (!diag) tot *= 2.0f;  // unordered pair counted once -> weight 2
        atomicAdd(out, tot);
    }
}

extern "C" void kernel_launch(void* const* d_in, const int* in_sizes, int n_in,
                              void* d_out, int out_size, void* d_ws, size_t ws_size,
                              hipStream_t stream) {
    const float2* kp = (const float2*)d_in[0];
    float* out = (float*)d_out;

    // d_out poisoned 0xAA before every timed launch -> zero on-stream.
    hipMemsetAsync(out, 0, sizeof(float), stream);

    dim3 grid(NTPAIRS, BATCHES);  // 136 x 32 = 4352 blocks = 17/CU exactly
    loss_sep_kernel<<<grid, TILE, 0, stream>>>(kp, out);
}

// Round 4
// 72.462 us; speedup vs baseline: 1.5473x; 1.5473x over previous
//
#include <hip/hip_runtime.h>

// loss_separation: sum_{b, i != j} exp(-0.5 * ||kp[b,i] - kp[b,j]||)
// B=32, N=2048 fp32 -> scalar fp32.
// Symmetry: sum = 2 * sum_{i<j}; upper-triangular 128x128 tile pairs.
// R4: replace 4352 same-address atomicAdds (serialization tail, ~65us)
// with per-block partial stores to d_ws + a stage-2 reduce kernel.

#define BATCHES 32
#define NPTS 2048
#define TILE 128
#define TTILES (NPTS / TILE)                 // 16
#define NTPAIRS (TTILES * (TTILES + 1) / 2)  // 136
#define NPARTS (NTPAIRS * BATCHES)           // 4352 = 17 * 256

__global__ __launch_bounds__(TILE)
void loss_sep_kernel(const float2* __restrict__ kp, float* __restrict__ part) {
    const int b = blockIdx.y;

    // Decode upper-triangular tile pair (ti <= tj); uniform scalar loop <=16 iters.
    int t = blockIdx.x;
    int ti = 0;
    while (t >= TTILES - ti) { t -= TTILES - ti; ++ti; }
    const int tj = ti + t;
    const bool diag = (ti == tj);

    const int i0 = ti * TILE;
    const int j0 = tj * TILE;
    const int tid = threadIdx.x;

    __shared__ float2 kj[TILE];
    kj[tid] = kp[(size_t)b * NPTS + j0 + tid];          // 8B/lane coalesced, 1 KB
    const float2 ki = kp[(size_t)b * NPTS + i0 + tid];
    __syncthreads();

    const float4* kj4 = reinterpret_cast<const float4*>(kj);
    const float c = -0.72134752044448169f;  // -0.5 * log2(e)

    float acc0 = 0.0f, acc1 = 0.0f;
    #pragma unroll 8
    for (int jj = 0; jj < TILE / 2; ++jj) {
        const float4 v = kj4[jj];           // ds_read_b128, wave-uniform broadcast
        const float dx0 = ki.x - v.x, dy0 = ki.y - v.y;
        const float dx1 = ki.x - v.z, dy1 = ki.y - v.w;
        const float s0 = __builtin_amdgcn_sqrtf(dx0 * dx0 + dy0 * dy0);
        const float s1 = __builtin_amdgcn_sqrtf(dx1 * dx1 + dy1 * dy1);
        acc0 += __builtin_amdgcn_exp2f(c * s0);  // exp(-0.5*s) == exp2(c*s)
        acc1 += __builtin_amdgcn_exp2f(c * s1);
    }
    float acc = acc0 + acc1;
    if (diag) acc -= 1.0f;  // remove exact j==i term (exp(0)=1)

    // Wave-64 butterfly reduce
    #pragma unroll
    for (int off = 32; off > 0; off >>= 1)
        acc += __shfl_down(acc, off, 64);

    __shared__ float wsum[TILE / 64];
    if ((tid & 63) == 0) wsum[tid >> 6] = acc;
    __syncthreads();

    if (tid == 0) {
        float tot = wsum[0] + wsum[1];
        if (!diag) tot *= 2.0f;  // unordered pair counted once -> weight 2
        part[b * NTPAIRS + blockIdx.x] = tot;  // contention-free store
    }
}

__global__ __launch_bounds__(256)
void loss_sep_reduce(const float* __restrict__ part, float* __restrict__ out) {
    const int tid = threadIdx.x;
    float acc = 0.0f;
    #pragma unroll
    for (int k = 0; k < NPARTS / 256; ++k)      // 17 coalesced strided loads
        acc += part[k * 256 + tid];

    #pragma unroll
    for (int off = 32; off > 0; off >>= 1)
        acc += __shfl_down(acc, off, 64);

    __shared__ float wsum[4];
    if ((tid & 63) == 0) wsum[tid >> 6] = acc;
    __syncthreads();

    if (tid == 0)
        out[0] = wsum[0] + wsum[1] + wsum[2] + wsum[3];
}

extern "C" void kernel_launch(void* const* d_in, const int* in_sizes, int n_in,
                              void* d_out, int out_size, void* d_ws, size_t ws_size,
                              hipStream_t stream) {
    const float2* kp = (const float2*)d_in[0];
    float* part = (float*)d_ws;   // NPARTS floats, fully overwritten each call
    float* out = (float*)d_out;

    dim3 grid(NTPAIRS, BATCHES);  // 136 x 32 = 4352 blocks = 17/CU exactly
    loss_sep_kernel<<<grid, TILE, 0, stream>>>(kp, part);
    loss_sep_reduce<<<1, 256, 0, stream>>>(part, out);
}

// Round 5
// 72.216 us; speedup vs baseline: 1.5526x; 1.0034x over previous
//
#include <hip/hip_runtime.h>

// loss_separation: sum_{b, i != j} exp(-0.5 * ||kp[b,i] - kp[b,j]||)
// B=32, N=2048 fp32 -> scalar fp32.
// Symmetry: sum = 2*sum_{i<j}; upper-tri 128x128 tile pairs; partial sums
// to d_ws + stage-2 reduce (R4: fixed atomic tail).
// R5: prescale coords by 0.5*log2(e) so exp(-0.5*sqrt(d2)) == exp2(-sqrt(d2')),
// saving the per-pair mul; 4 accumulators / 4 pairs per iter for ILP.

#define BATCHES 32
#define NPTS 2048
#define TILE 128
#define TTILES (NPTS / TILE)                 // 16
#define NTPAIRS (TTILES * (TTILES + 1) / 2)  // 136
#define NPARTS (NTPAIRS * BATCHES)           // 4352 = 17 * 256

__global__ __launch_bounds__(TILE)
void loss_sep_kernel(const float2* __restrict__ kp, float* __restrict__ part) {
    const int b = blockIdx.y;

    // Decode upper-triangular tile pair (ti <= tj).
    int t = blockIdx.x;
    int ti = 0;
    while (t >= TTILES - ti) { t -= TTILES - ti; ++ti; }
    const int tj = ti + t;
    const bool diag = (ti == tj);

    const int i0 = ti * TILE;
    const int j0 = tj * TILE;
    const int tid = threadIdx.x;

    const float c = 0.72134752044448169f;  // 0.5 * log2(e)

    __shared__ float2 kj[TILE];
    {
        const float2 v = kp[(size_t)b * NPTS + j0 + tid];
        kj[tid] = make_float2(c * v.x, c * v.y);     // prescaled
    }
    float2 ki = kp[(size_t)b * NPTS + i0 + tid];
    ki.x *= c; ki.y *= c;
    __syncthreads();

    const float4* kj4 = reinterpret_cast<const float4*>(kj);

    float acc0 = 0.0f, acc1 = 0.0f, acc2 = 0.0f, acc3 = 0.0f;
    #pragma unroll 4
    for (int jj = 0; jj < TILE / 4; ++jj) {
        const float4 va = kj4[2 * jj];       // j pairs 0,1 (broadcast b128)
        const float4 vb = kj4[2 * jj + 1];   // j pairs 2,3
        const float dx0 = ki.x - va.x, dy0 = ki.y - va.y;
        const float dx1 = ki.x - va.z, dy1 = ki.y - va.w;
        const float dx2 = ki.x - vb.x, dy2 = ki.y - vb.y;
        const float dx3 = ki.x - vb.z, dy3 = ki.y - vb.w;
        const float s0 = __builtin_amdgcn_sqrtf(dx0 * dx0 + dy0 * dy0);
        const float s1 = __builtin_amdgcn_sqrtf(dx1 * dx1 + dy1 * dy1);
        const float s2 = __builtin_amdgcn_sqrtf(dx2 * dx2 + dy2 * dy2);
        const float s3 = __builtin_amdgcn_sqrtf(dx3 * dx3 + dy3 * dy3);
        acc0 += __builtin_amdgcn_exp2f(-s0);  // v_exp_f32 with neg modifier
        acc1 += __builtin_amdgcn_exp2f(-s1);
        acc2 += __builtin_amdgcn_exp2f(-s2);
        acc3 += __builtin_amdgcn_exp2f(-s3);
    }
    float acc = (acc0 + acc1) + (acc2 + acc3);
    if (diag) acc -= 1.0f;  // remove exact j==i term (exp2(-0)=1)

    // Wave-64 butterfly reduce
    #pragma unroll
    for (int off = 32; off > 0; off >>= 1)
        acc += __shfl_down(acc, off, 64);

    __shared__ float wsum[TILE / 64];
    if ((tid & 63) == 0) wsum[tid >> 6] = acc;
    __syncthreads();

    if (tid == 0) {
        float tot = wsum[0] + wsum[1];
        if (!diag) tot *= 2.0f;  // unordered pair counted once -> weight 2
        part[b * NTPAIRS + blockIdx.x] = tot;  // contention-free store
    }
}

__global__ __launch_bounds__(256)
void loss_sep_reduce(const float* __restrict__ part, float* __restrict__ out) {
    const int tid = threadIdx.x;
    float acc = 0.0f;
    #pragma unroll
    for (int k = 0; k < NPARTS / 256; ++k)      // 17 coalesced strided loads
        acc += part[k * 256 + tid];

    #pragma unroll
    for (int off = 32; off > 0; off >>= 1)
        acc += __shfl_down(acc, off, 64);

    __shared__ float wsum[4];
    if ((tid & 63) == 0) wsum[tid >> 6] = acc;
    __syncthreads();

    if (tid == 0)
        out[0] = wsum[0] + wsum[1] + wsum[2] + wsum[3];
}

extern "C" void kernel_launch(void* const* d_in, const int* in_sizes, int n_in,
                              void* d_out, int out_size, void* d_ws, size_t ws_size,
                              hipStream_t stream) {
    const float2* kp = (const float2*)d_in[0];
    float* part = (float*)d_ws;   // NPARTS floats, fully overwritten each call
    float* out = (float*)d_out;

    dim3 grid(NTPAIRS, BATCHES);  // 136 x 32 = 4352 blocks
    loss_sep_kernel<<<grid, TILE, 0, stream>>>(kp, part);
    loss_sep_reduce<<<1, 256, 0, stream>>>(part, out);
}